// Round 15
// baseline (477.791 us; speedup 1.0000x reference)
//
#include <hip/hip_runtime.h>
#include <stdint.h>

#define LOG2E  1.4426950408889634f
#define LN2    0.6931471805599453f
#define BIAS_E 32   // deferred-rescale normalization target: 2^BIAS_E

typedef float v4f __attribute__((ext_vector_type(4)));

// lane i <- lane i-1 (wave_shr:1 = 0x138), lane 0 <- 0.0f (bound_ctrl=true)
__device__ __forceinline__ float dpp_shr1_z(float x) {
  int r = __builtin_amdgcn_update_dpp(0, __float_as_int(x), 0x138, 0xf, 0xf, true);
  return __int_as_float(r);
}

template <int CTRL>
__device__ __forceinline__ float dpp_max(float v) {
  int r = __builtin_amdgcn_update_dpp(0, __float_as_int(v), CTRL, 0xf, 0xf, true);
  return fmaxf(v, __int_as_float(r));
}

// wave64 max reduce -> uniform value (lane63 readlane). alpha >= 0 so 0-fill ok.
__device__ __forceinline__ float wave_max_uniform(float v) {
  v = dpp_max<0x111>(v);   // row_shr:1
  v = dpp_max<0x112>(v);   // row_shr:2
  v = dpp_max<0x114>(v);   // row_shr:4
  v = dpp_max<0x118>(v);   // row_shr:8
  v = dpp_max<0x142>(v);   // row_bcast15
  v = dpp_max<0x143>(v);   // row_bcast31 -> lane 63 = global max
  int gm = __builtin_amdgcn_readlane(__float_as_int(v), 63);
  return __int_as_float(gm);
}

__device__ __forceinline__ uint32_t ldcnt(const uint32_t* p) {
  return __hip_atomic_load(p, __ATOMIC_RELAXED, __HIP_MEMORY_SCOPE_AGENT);
}

// ============================================================================
// Fused kernel. Grid = B consumer blocks (idx 0..B-1, dispatched first) +
// B*PCH producer blocks. 256 threads each.
//
// Producer block g (g = blockIdx-B): batch pb = g%B, t-chunk tch = g/B; its
// 4 waves compute softmax-gather rows t = 4*tch..4*tch+3 into lp[pb][c][t]
// (transposed linear-prob layout, proven rounds 9-14). Batch-interleaved
// mapping => window w of EVERY batch completes at ~ (w/NW) of producer span,
// so consumers stream right behind. After its rows: threadfence + atomicAdd
// to cnt[pb][tch/4] (decoupled-lookback flag).
//
// Consumer block b (wave 0 only): round-14 recurrence (LINEAR domain,
// deferred+biased power-of-2 rescale, asm label loads + post-wait copies,
// qb/nb blank double-buffer) with per-window gating: poll cnt[b][w] >= tgt(w)
// (agent-scope atomic, value prefetched one window early so the check is
// usually free), threadfence acquire, then load. Producers never wait =>
// no deadlock regardless of dispatch order; worst case is serial (= today).
// ============================================================================
__global__ __launch_bounds__(256, 1) void k_fused(
    const float* __restrict__ acts, const int* __restrict__ labels,
    const int* __restrict__ act_lens, const int* __restrict__ label_lens,
    float* __restrict__ lp, float* __restrict__ lossb, uint32_t* __restrict__ cnt,
    int T, int Tp, int B, int V, int L, int PCH, int NW) {

  __shared__ float A_[132];

  if (blockIdx.x >= (uint32_t)B) {
    // ---------------- producer ----------------
    const int g   = blockIdx.x - B;
    const int pb  = g % B;
    const int tch = g / B;
    const int wv  = threadIdx.x >> 6;
    const int lane = threadIdx.x & 63;
    const int t = tch * 4 + wv;
    if (t < T) {
      const float* __restrict__ row = acts + ((size_t)t * (size_t)B + pb) * (size_t)V;
      float mx, l2s;
      if (V == 2048) {
        const float4* row4 = (const float4*)row;
        float vals[32];
        mx = -3.0e38f;
#pragma unroll
        for (int q = 0; q < 8; ++q) {
          float4 v = row4[lane + (q << 6)];
          vals[q*4+0] = v.x; vals[q*4+1] = v.y; vals[q*4+2] = v.z; vals[q*4+3] = v.w;
          mx = fmaxf(mx, fmaxf(fmaxf(v.x, v.y), fmaxf(v.z, v.w)));
        }
#pragma unroll
        for (int off = 32; off >= 1; off >>= 1) mx = fmaxf(mx, __shfl_xor(mx, off, 64));
        float s = 0.0f;
#pragma unroll
        for (int k = 0; k < 32; ++k) s += exp2f((vals[k] - mx) * LOG2E);
#pragma unroll
        for (int off = 32; off >= 1; off >>= 1) s += __shfl_xor(s, off, 64);
        l2s = log2f(s);
      } else {
        float m = -3.0e38f, s = 0.0f;
        for (int i = lane; i < V; i += 64) {
          float x = row[i];
          float m2 = fmaxf(m, x);
          s = s * exp2f((m - m2) * LOG2E) + exp2f((x - m2) * LOG2E);
          m = m2;
        }
#pragma unroll
        for (int off = 32; off >= 1; off >>= 1) {
          float mo = __shfl_xor(m, off, 64), so = __shfl_xor(s, off, 64);
          float m2 = fmaxf(m, mo);
          s = s * exp2f((m - m2) * LOG2E) + so * exp2f((mo - m2) * LOG2E);
          m = m2;
        }
        mx = m;
        l2s = log2f(s);
      }
      float* __restrict__ out = lp + (size_t)pb * (size_t)(L + 1) * (size_t)Tp;
      if (lane < L) {
        int lab = labels[pb * (uint32_t)L + lane];
        out[(size_t)(1 + lane) * Tp + t] = exp2f((row[lab] - mx) * LOG2E - l2s);
      }
      if (lane == 0) out[t] = exp2f((row[0] - mx) * LOG2E - l2s);
    }
    __syncthreads();
    if (threadIdx.x == 0) {
      __threadfence();                       // release: rows visible device-wide
      atomicAdd(&cnt[(size_t)pb * 64 + (tch >> 2)], 1u);
    }
    return;
  }

  // ---------------- consumer ----------------
  if (threadIdx.x >= 64) return;
  const int b = blockIdx.x;
  const int lane = threadIdx.x;
  const int Tact = __builtin_amdgcn_readfirstlane(min(act_lens[b], T));
  const int ll   = __builtin_amdgcn_readfirstlane(min(label_lens[b], L));

  const float* __restrict__ chb = lp + (size_t)b * (size_t)(L + 1) * (size_t)Tp;
  const int lclamp = (lane < L) ? lane : (L - 1);
  const float* __restrict__ chl = chb + (size_t)(1 + lclamp) * (size_t)Tp;
  const uint32_t* cb = cnt + (size_t)b * 64;
  const int wlast = NW - 1;

  int lab_i = (lane < L) ? labels[(size_t)b * L + lane] : 0;
  int lab_p = (lane >= 1 && lane - 1 < L) ? labels[(size_t)b * L + lane - 1] : -1;
  const bool allow2 = (lane >= 1) && (lab_i != 0) && (lab_i != lab_p);

  v4f r0, r1, r2, r3;          // label window in flight (asm outputs)
  v4f d0, d1, d2, d3;          // label window, landed
  float4 qb0, qb1, qb2, qb3;   // blank window, current
  float4 nb0, nb1, nb2, nb3;   // blank window, next
  int acc_e = 0;
  int pend_e = 0;
  float pend_sc = 1.0f;

#define TGTW(w) ((uint32_t)(((PCH - 4*(w)) >= 4) ? 4 : (PCH - 4*(w))))
#define POLLW(w) { while (ldcnt(cb + (w)) < TGTW(w)) __builtin_amdgcn_s_sleep(8); }

  asm volatile("s_waitcnt vmcnt(0) lgkmcnt(0)" ::: "memory");
  __builtin_amdgcn_sched_barrier(0);

#define LOADR(tt) { int tc = (tt); if (tc > Tp - 16) tc = Tp - 16;           \
    const float* p_ = chl + tc;                                              \
    asm volatile("global_load_dwordx4 %0, %4, off\n\t"                       \
                 "global_load_dwordx4 %1, %4, off offset:16\n\t"             \
                 "global_load_dwordx4 %2, %4, off offset:32\n\t"             \
                 "global_load_dwordx4 %3, %4, off offset:48"                 \
                 : "=&v"(r0), "=&v"(r1), "=&v"(r2), "=&v"(r3) : "v"(p_)); }

#define WAITR asm volatile("s_waitcnt vmcnt(0)"                              \
                 : "+v"(r0), "+v"(r1), "+v"(r2), "+v"(r3));

#define COPYD { d0 = r0; d1 = r1; d2 = r2; d3 = r3; }

#define LOADB(D, tt) { int tc = (tt); if (tc > Tp - 16) tc = Tp - 16;        \
    const float4* pb4 = (const float4*)(chb + tc);                           \
    D##0 = pb4[0]; D##1 = pb4[1]; D##2 = pb4[2]; D##3 = pb4[3]; }

#define ST(PB, PL) { float pa = dpp_shr1_z(s1);                              \
    float cc = allow2 ? pa : 0.0f;                                           \
    float n0 = (s0 + pa) * (PB);                                             \
    float n1 = ((s0 + s1) + cc) * (PL);                                      \
    float n2 = (s2 + s1) * (PB);                                             \
    s0 = n0; s1 = n1; s2 = n2; }

#define RESC { s0 *= pend_sc; s1 *= pend_sc; s2 *= pend_sc; acc_e += pend_e; \
    float gm = wave_max_uniform(fmaxf(fmaxf(s0, s1), s2));                   \
    int e = ((__float_as_int(gm) >> 23) & 0xff) - 127 - BIAS_E;              \
    if (e < -126) e = -126;                                                  \
    pend_e = e;                                                              \
    pend_sc = __int_as_float((127 - e) << 23); }

#define STG(PB, PL, tt) { if ((tt) >= 1 && (tt) < Tact) ST(PB, PL) }

#define WIN16 {                                                              \
    ST(qb0.x, d0.x) ST(qb0.y, d0.y) ST(qb0.z, d0.z) ST(qb0.w, d0.w) RESC     \
    ST(qb1.x, d1.x) ST(qb1.y, d1.y) ST(qb1.z, d1.z) ST(qb1.w, d1.w) RESC     \
    ST(qb2.x, d2.x) ST(qb2.y, d2.y) ST(qb2.z, d2.z) ST(qb2.w, d2.w) RESC     \
    ST(qb3.x, d3.x) ST(qb3.y, d3.y) ST(qb3.z, d3.z) ST(qb3.w, d3.w) RESC }

#define WIN16G(tb) {                                                         \
    STG(qb0.x, d0.x, (tb)+0)  STG(qb0.y, d0.y, (tb)+1)                       \
    STG(qb0.z, d0.z, (tb)+2)  STG(qb0.w, d0.w, (tb)+3)  RESC                 \
    STG(qb1.x, d1.x, (tb)+4)  STG(qb1.y, d1.y, (tb)+5)                       \
    STG(qb1.z, d1.z, (tb)+6)  STG(qb1.w, d1.w, (tb)+7)  RESC                 \
    STG(qb2.x, d2.x, (tb)+8)  STG(qb2.y, d2.y, (tb)+9)                       \
    STG(qb2.z, d2.z, (tb)+10) STG(qb2.w, d2.w, (tb)+11) RESC                 \
    STG(qb3.x, d3.x, (tb)+12) STG(qb3.y, d3.y, (tb)+13)                      \
    STG(qb3.z, d3.z, (tb)+14) STG(qb3.w, d3.w, (tb)+15) RESC }

#define SWAPB { qb0 = nb0; qb1 = nb1; qb2 = nb2; qb3 = nb3; }

  // ---- prologue: gate windows 0..2, then round-14 prologue ----
  POLLW(0)
  { int w_ = (1 < wlast) ? 1 : wlast; POLLW(w_) }
  { int w_ = (2 < wlast) ? 2 : wlast; POLLW(w_) }
  __threadfence();            // acquire: produced rows readable

  LOADR(0)
  LOADB(qb, 0)                // blank window 0
  LOADB(nb, 16)               // blank window 1
  WAITR
  COPYD
  LOADR(16)                   // label window 1 in flight across WIN16

  float s0 = (lane == 0) ? qb0.x : 0.0f;   // alpha[0] = p_blank(0)
  float s1 = (lane == 0) ? d0.x  : 0.0f;   // alpha[1] = p_label0(0)
  float s2 = 0.0f;

  WIN16G(0)                   // t=1..15 (t=0 skipped by guard)
  SWAPB LOADB(nb, 32)         // window 2 (gated above)
  uint32_t cv1 = ldcnt(cb + ((2 < wlast) ? 2 : wlast));
  uint32_t cv2 = ldcnt(cb + ((3 < wlast) ? 3 : wlast));
  int t0 = 16;

  // ---- main loop ----
  while (t0 + 16 <= Tact) {
    WAITR
    COPYD
    { const int w = t0 >> 4;
      const int w1 = (w + 1 < wlast) ? w + 1 : wlast;   // for LOADR(t0+16)
      const int w2 = (w + 2 < wlast) ? w + 2 : wlast;   // for LOADB(t0+32)
      if (cv1 < TGTW(w1)) POLLW(w1)
      if (cv2 < TGTW(w2)) POLLW(w2)
      __threadfence();        // acquire before reading the gated windows
      LOADR(t0 + 16)
      WIN16
      SWAPB LOADB(nb, t0 + 32)
      cv1 = ldcnt(cb + ((w + 2 < wlast) ? w + 2 : wlast));  // prefetch checks
      cv2 = ldcnt(cb + ((w + 3 < wlast) ? w + 3 : wlast));
    }
    t0 += 16;
  }

  // ---- tail ----
  if (t0 < Tact) {
    WAITR
    COPYD
    WIN16G(t0)
  }

#undef LOADR
#undef WAITR
#undef COPYD
#undef LOADB
#undef ST
#undef RESC
#undef STG
#undef WIN16
#undef WIN16G
#undef SWAPB
#undef TGTW
#undef POLLW

  A_[2 * lane] = s0;
  A_[2 * lane + 1] = s1;
  if (lane == 63) A_[128] = s2;
  __builtin_amdgcn_sched_barrier(0);   // same-wave LDS: lgkmcnt ordering only
  if (lane == 0) {
    int sl = 2 * ll;
    float a1 = A_[sl];
    float a2 = (sl >= 1) ? A_[sl - 1] : 0.0f;
    // true alpha = stored * 2^{acc_e} (pend_* intentionally unapplied)
    lossb[b] = -(logf(a1 + a2) + (float)acc_e * LN2);
  }
}

// ============================================================================
// Sum per-batch losses -> d_out[0]
// ============================================================================
__global__ __launch_bounds__(64) void k_sum(const float* __restrict__ loss,
                                            float* __restrict__ out, int B) {
  int lane = threadIdx.x;
  float s = 0.0f;
  for (int i = lane; i < B; i += 64) s += loss[i];
#pragma unroll
  for (int off = 32; off >= 1; off >>= 1) s += __shfl_xor(s, off, 64);
  if (lane == 0) out[0] = s;
}

extern "C" void kernel_launch(void* const* d_in, const int* in_sizes, int n_in,
                              void* d_out, int out_size, void* d_ws, size_t ws_size,
                              hipStream_t stream) {
  const float* acts       = (const float*)d_in[0];
  const int*   labels     = (const int*)d_in[1];
  const int*   act_lens   = (const int*)d_in[2];
  const int*   label_lens = (const int*)d_in[3];

  const int B = in_sizes[2];
  const int L = in_sizes[1] / B;
  const int T = 1000;   // per reference setup_inputs
  const int V = (int)((long long)in_sizes[0] / ((long long)T * (long long)B));
  const int Tp  = (T + 31) & ~31;   // padded channel stride (1024 for T=1000)
  const int PCH = (T + 3) / 4;      // producer t-chunks per batch (250)
  const int NW  = (T + 15) / 16;    // windows per batch (63)

  float*    lp    = (float*)d_ws;                            // B*(L+1)*Tp floats
  float*    lossb = lp + (size_t)B * (size_t)(L + 1) * (size_t)Tp;
  uint32_t* cnt   = (uint32_t*)(lossb + B);                  // B*64 u32 flags

  hipMemsetAsync(cnt, 0, (size_t)B * 64 * sizeof(uint32_t), stream);
  k_fused<<<dim3(B + B * PCH), dim3(256), 0, stream>>>(
      acts, labels, act_lens, label_lens, lp, lossb, cnt, T, Tp, B, V, L, PCH, NW);
  k_sum<<<dim3(1), dim3(64), 0, stream>>>(lossb, (float*)d_out, B);
}

// Round 16
// 164.277 us; speedup vs baseline: 2.9085x; 2.9085x over previous
//
#include <hip/hip_runtime.h>
#include <stdint.h>

#define LOG2E  1.4426950408889634f
#define LN2    0.6931471805599453f
#define BIAS_E 32   // deferred-rescale normalization target: 2^BIAS_E

typedef float v4f __attribute__((ext_vector_type(4)));

// lane i <- lane i-1 (wave_shr:1 = 0x138), lane 0 <- 0.0f (bound_ctrl=true)
__device__ __forceinline__ float dpp_shr1_z(float x) {
  int r = __builtin_amdgcn_update_dpp(0, __float_as_int(x), 0x138, 0xf, 0xf, true);
  return __int_as_float(r);
}

template <int CTRL>
__device__ __forceinline__ float dpp_max(float v) {
  int r = __builtin_amdgcn_update_dpp(0, __float_as_int(v), CTRL, 0xf, 0xf, true);
  return fmaxf(v, __int_as_float(r));
}

// wave64 max reduce -> uniform value (lane63 readlane). alpha >= 0 so 0-fill ok.
__device__ __forceinline__ float wave_max_uniform(float v) {
  v = dpp_max<0x111>(v);   // row_shr:1
  v = dpp_max<0x112>(v);   // row_shr:2
  v = dpp_max<0x114>(v);   // row_shr:4
  v = dpp_max<0x118>(v);   // row_shr:8
  v = dpp_max<0x142>(v);   // row_bcast15
  v = dpp_max<0x143>(v);   // row_bcast31 -> lane 63 = global max
  int gm = __builtin_amdgcn_readlane(__float_as_int(v), 63);
  return __int_as_float(gm);
}

// ============================================================================
// Kernel 1: per (t,b) row: softmax over V, emit LINEAR probs, transposed
// layout lp[b][c][t], c=0 blank, c=1..L labels, channel stride Tp floats.
// (round-14 version, unchanged)
// ============================================================================
__global__ __launch_bounds__(256) void k_prob_gather(
    const float* __restrict__ acts, const int* __restrict__ labels,
    float* __restrict__ lp, int T, int Tp, int B, int V, int L) {
  const int lane = threadIdx.x & 63;
  const uint32_t r = blockIdx.x * 4u + (threadIdx.x >> 6);
  if (r >= (uint32_t)(T * B)) return;
  const uint32_t b = r / (uint32_t)T;
  const uint32_t t = r % (uint32_t)T;
  const float* __restrict__ row = acts + ((size_t)t * (size_t)B + b) * (size_t)V;

  float mx, l2s;
  if (V == 2048) {
    const float4* row4 = (const float4*)row;
    float vals[32];
    mx = -3.0e38f;
#pragma unroll
    for (int q = 0; q < 8; ++q) {
      float4 v = row4[lane + (q << 6)];
      vals[q*4+0] = v.x; vals[q*4+1] = v.y; vals[q*4+2] = v.z; vals[q*4+3] = v.w;
      mx = fmaxf(mx, fmaxf(fmaxf(v.x, v.y), fmaxf(v.z, v.w)));
    }
#pragma unroll
    for (int off = 32; off >= 1; off >>= 1) mx = fmaxf(mx, __shfl_xor(mx, off, 64));
    float s = 0.0f;
#pragma unroll
    for (int k = 0; k < 32; ++k) s += exp2f((vals[k] - mx) * LOG2E);
#pragma unroll
    for (int off = 32; off >= 1; off >>= 1) s += __shfl_xor(s, off, 64);
    l2s = log2f(s);
  } else {
    float m = -3.0e38f, s = 0.0f;
    for (int i = lane; i < V; i += 64) {
      float x = row[i];
      float m2 = fmaxf(m, x);
      s = s * exp2f((m - m2) * LOG2E) + exp2f((x - m2) * LOG2E);
      m = m2;
    }
#pragma unroll
    for (int off = 32; off >= 1; off >>= 1) {
      float mo = __shfl_xor(m, off, 64), so = __shfl_xor(s, off, 64);
      float m2 = fmaxf(m, mo);
      s = s * exp2f((m - m2) * LOG2E) + so * exp2f((mo - m2) * LOG2E);
      m = m2;
    }
    mx = m;
    l2s = log2f(s);
  }

  float* __restrict__ out = lp + (size_t)b * (size_t)(L + 1) * (size_t)Tp;
  if (lane < L) {
    int lab = labels[b * (uint32_t)L + lane];
    out[(size_t)(1 + lane) * Tp + t] = exp2f((row[lab] - mx) * LOG2E - l2s);
  }
  if (lane == 0) out[t] = exp2f((row[0] - mx) * LOG2E - l2s);
}

// ============================================================================
// Kernel 2: CTC forward, LINEAR domain, deferred+biased power-of-2 rescale
// (round-14 numerics, proven absmax 3072). NEW: TWO independent batch
// recurrences per wave (bA = blockIdx, bB = bA + B/2) — the single-wave
// recurrence is latency-bound (per-active-CU VALUBusy ~19%), so a second
// independent chain fills the stall slots (ILP, since TLP is impossible).
// Extra RESCs after a batch's Tact are exact no-ops on the tracked value
// (power-of-2 scale + exponent accumulator), so differing act_lens are safe.
// ============================================================================
__global__ __launch_bounds__(64, 1) void k_ctc_fwd(
    const float* __restrict__ lp, const int* __restrict__ labels,
    const int* __restrict__ act_lens, const int* __restrict__ label_lens,
    float* __restrict__ loss, int T, int Tp, int B, int L) {
  const int bA = blockIdx.x;
  const int nP = (B + 1) >> 1;
  const int bBr = bA + nP;
  const bool hasB = (bBr < B);
  const int bB = hasB ? bBr : bA;
  const int lane = threadIdx.x;

  const int TactA = __builtin_amdgcn_readfirstlane(min(act_lens[bA], T));
  const int TactB = __builtin_amdgcn_readfirstlane(min(act_lens[bB], T));
  const int llA   = __builtin_amdgcn_readfirstlane(min(label_lens[bA], L));
  const int llB   = __builtin_amdgcn_readfirstlane(min(label_lens[bB], L));
  const int Tmin = (TactA < TactB) ? TactA : TactB;
  const int Tmax = (TactA > TactB) ? TactA : TactB;

  const float* __restrict__ chbA = lp + (size_t)bA * (size_t)(L + 1) * (size_t)Tp;
  const float* __restrict__ chbB = lp + (size_t)bB * (size_t)(L + 1) * (size_t)Tp;
  const int lclamp = (lane < L) ? lane : (L - 1);
  const float* __restrict__ chlA = chbA + (size_t)(1 + lclamp) * (size_t)Tp;
  const float* __restrict__ chlB = chbB + (size_t)(1 + lclamp) * (size_t)Tp;

  int labA_i = (lane < L) ? labels[(size_t)bA * L + lane] : 0;
  int labA_p = (lane >= 1 && lane - 1 < L) ? labels[(size_t)bA * L + lane - 1] : -1;
  const bool allow2A = (lane >= 1) && (labA_i != 0) && (labA_i != labA_p);
  int labB_i = (lane < L) ? labels[(size_t)bB * L + lane] : 0;
  int labB_p = (lane >= 1 && lane - 1 < L) ? labels[(size_t)bB * L + lane - 1] : -1;
  const bool allow2B = (lane >= 1) && (labB_i != 0) && (labB_i != labB_p);

  __shared__ float A_[264];

  v4f rA0, rA1, rA2, rA3, rB0, rB1, rB2, rB3;   // in flight (asm outputs)
  v4f dA0, dA1, dA2, dA3, dB0, dB1, dB2, dB3;   // landed copies
  float4 qbA0, qbA1, qbA2, qbA3, nbA0, nbA1, nbA2, nbA3;
  float4 qbB0, qbB1, qbB2, qbB3, nbB0, nbB1, nbB2, nbB3;
  int acc_eA = 0, pend_eA = 0;  float pend_scA = 1.0f;
  int acc_eB = 0, pend_eB = 0;  float pend_scB = 1.0f;

  asm volatile("s_waitcnt vmcnt(0) lgkmcnt(0)" ::: "memory");
  __builtin_amdgcn_sched_barrier(0);

#define LOADR(tt) { int tc = (tt); if (tc > Tp - 16) tc = Tp - 16;           \
    const float* pA_ = chlA + tc; const float* pB_ = chlB + tc;              \
    asm volatile("global_load_dwordx4 %0, %8, off\n\t"                       \
                 "global_load_dwordx4 %1, %8, off offset:16\n\t"             \
                 "global_load_dwordx4 %2, %8, off offset:32\n\t"             \
                 "global_load_dwordx4 %3, %8, off offset:48\n\t"             \
                 "global_load_dwordx4 %4, %9, off\n\t"                       \
                 "global_load_dwordx4 %5, %9, off offset:16\n\t"             \
                 "global_load_dwordx4 %6, %9, off offset:32\n\t"             \
                 "global_load_dwordx4 %7, %9, off offset:48"                 \
                 : "=&v"(rA0), "=&v"(rA1), "=&v"(rA2), "=&v"(rA3),           \
                   "=&v"(rB0), "=&v"(rB1), "=&v"(rB2), "=&v"(rB3)            \
                 : "v"(pA_), "v"(pB_)); }

#define WAITR asm volatile("s_waitcnt vmcnt(0)"                              \
    : "+v"(rA0), "+v"(rA1), "+v"(rA2), "+v"(rA3),                            \
      "+v"(rB0), "+v"(rB1), "+v"(rB2), "+v"(rB3));

#define COPYD { dA0 = rA0; dA1 = rA1; dA2 = rA2; dA3 = rA3;                  \
                dB0 = rB0; dB1 = rB1; dB2 = rB2; dB3 = rB3; }

#define LOADB(D, tt) { int tc = (tt); if (tc > Tp - 16) tc = Tp - 16;        \
    const float4* pA4 = (const float4*)(chbA + tc);                          \
    const float4* pB4 = (const float4*)(chbB + tc);                          \
    D##A0 = pA4[0]; D##A1 = pA4[1]; D##A2 = pA4[2]; D##A3 = pA4[3];          \
    D##B0 = pB4[0]; D##B1 = pB4[1]; D##B2 = pB4[2]; D##B3 = pB4[3]; }

#define STA(PB, PL) { float pa = dpp_shr1_z(s1A);                            \
    float cc = allow2A ? pa : 0.0f;                                          \
    float n0 = (s0A + pa) * (PB);                                            \
    float n1 = ((s0A + s1A) + cc) * (PL);                                    \
    float n2 = (s2A + s1A) * (PB);                                           \
    s0A = n0; s1A = n1; s2A = n2; }

#define STB(PB, PL) { float pa = dpp_shr1_z(s1B);                            \
    float cc = allow2B ? pa : 0.0f;                                          \
    float n0 = (s0B + pa) * (PB);                                            \
    float n1 = ((s0B + s1B) + cc) * (PL);                                    \
    float n2 = (s2B + s1B) * (PB);                                           \
    s0B = n0; s1B = n1; s2B = n2; }

#define STAB(PBA, PLA, PBB, PLB) { STA(PBA, PLA) STB(PBB, PLB) }

#define RESC {                                                               \
    s0A *= pend_scA; s1A *= pend_scA; s2A *= pend_scA; acc_eA += pend_eA;    \
    s0B *= pend_scB; s1B *= pend_scB; s2B *= pend_scB; acc_eB += pend_eB;    \
    float gmA = wave_max_uniform(fmaxf(fmaxf(s0A, s1A), s2A));               \
    float gmB = wave_max_uniform(fmaxf(fmaxf(s0B, s1B), s2B));               \
    int eA = ((__float_as_int(gmA) >> 23) & 0xff) - 127 - BIAS_E;            \
    int eB = ((__float_as_int(gmB) >> 23) & 0xff) - 127 - BIAS_E;            \
    if (eA < -126) eA = -126;                                                \
    if (eB < -126) eB = -126;                                                \
    pend_eA = eA; pend_scA = __int_as_float((127 - eA) << 23);               \
    pend_eB = eB; pend_scB = __int_as_float((127 - eB) << 23); }

#define STGAB(PBA, PLA, PBB, PLB, tt) {                                      \
    if ((tt) >= 1 && (tt) < TactA) STA(PBA, PLA)                             \
    if ((tt) >= 1 && (tt) < TactB) STB(PBB, PLB) }

#define WIN16 {                                                                        \
    STAB(qbA0.x, dA0.x, qbB0.x, dB0.x) STAB(qbA0.y, dA0.y, qbB0.y, dB0.y)              \
    STAB(qbA0.z, dA0.z, qbB0.z, dB0.z) STAB(qbA0.w, dA0.w, qbB0.w, dB0.w) RESC         \
    STAB(qbA1.x, dA1.x, qbB1.x, dB1.x) STAB(qbA1.y, dA1.y, qbB1.y, dB1.y)              \
    STAB(qbA1.z, dA1.z, qbB1.z, dB1.z) STAB(qbA1.w, dA1.w, qbB1.w, dB1.w) RESC         \
    STAB(qbA2.x, dA2.x, qbB2.x, dB2.x) STAB(qbA2.y, dA2.y, qbB2.y, dB2.y)              \
    STAB(qbA2.z, dA2.z, qbB2.z, dB2.z) STAB(qbA2.w, dA2.w, qbB2.w, dB2.w) RESC         \
    STAB(qbA3.x, dA3.x, qbB3.x, dB3.x) STAB(qbA3.y, dA3.y, qbB3.y, dB3.y)              \
    STAB(qbA3.z, dA3.z, qbB3.z, dB3.z) STAB(qbA3.w, dA3.w, qbB3.w, dB3.w) RESC }

#define WIN16G(tb) {                                                                   \
    STGAB(qbA0.x, dA0.x, qbB0.x, dB0.x, (tb)+0)                                        \
    STGAB(qbA0.y, dA0.y, qbB0.y, dB0.y, (tb)+1)                                        \
    STGAB(qbA0.z, dA0.z, qbB0.z, dB0.z, (tb)+2)                                        \
    STGAB(qbA0.w, dA0.w, qbB0.w, dB0.w, (tb)+3)  RESC                                  \
    STGAB(qbA1.x, dA1.x, qbB1.x, dB1.x, (tb)+4)                                        \
    STGAB(qbA1.y, dA1.y, qbB1.y, dB1.y, (tb)+5)                                        \
    STGAB(qbA1.z, dA1.z, qbB1.z, dB1.z, (tb)+6)                                        \
    STGAB(qbA1.w, dA1.w, qbB1.w, dB1.w, (tb)+7)  RESC                                  \
    STGAB(qbA2.x, dA2.x, qbB2.x, dB2.x, (tb)+8)                                        \
    STGAB(qbA2.y, dA2.y, qbB2.y, dB2.y, (tb)+9)                                        \
    STGAB(qbA2.z, dA2.z, qbB2.z, dB2.z, (tb)+10)                                       \
    STGAB(qbA2.w, dA2.w, qbB2.w, dB2.w, (tb)+11) RESC                                  \
    STGAB(qbA3.x, dA3.x, qbB3.x, dB3.x, (tb)+12)                                       \
    STGAB(qbA3.y, dA3.y, qbB3.y, dB3.y, (tb)+13)                                       \
    STGAB(qbA3.z, dA3.z, qbB3.z, dB3.z, (tb)+14)                                       \
    STGAB(qbA3.w, dA3.w, qbB3.w, dB3.w, (tb)+15) RESC }

#define SWAPB { qbA0 = nbA0; qbA1 = nbA1; qbA2 = nbA2; qbA3 = nbA3;          \
                qbB0 = nbB0; qbB1 = nbB1; qbB2 = nbB2; qbB3 = nbB3; }

  // ---- prologue: window 0 ----
  LOADR(0)
  LOADB(qb, 0)
  LOADB(nb, 16)
  WAITR
  COPYD
  LOADR(16)

  float s0A = (lane == 0) ? qbA0.x : 0.0f;
  float s1A = (lane == 0) ? dA0.x  : 0.0f;
  float s2A = 0.0f;
  float s0B = (lane == 0) ? qbB0.x : 0.0f;
  float s1B = (lane == 0) ? dB0.x  : 0.0f;
  float s2B = 0.0f;

  WIN16G(0)                   // t=1..15 (t=0 skipped by guard)
  SWAPB LOADB(nb, 32)
  int t0 = 16;

  // ---- main loop (both batches active) ----
  while (t0 + 16 <= Tmin) {
    WAITR
    COPYD
    LOADR(t0 + 16)
    WIN16
    SWAPB LOADB(nb, t0 + 32)
    t0 += 16;
  }
  // ---- guarded windows until the longer batch finishes ----
  while (t0 < Tmax) {
    WAITR
    COPYD
    LOADR(t0 + 16)
    WIN16G(t0)
    SWAPB LOADB(nb, t0 + 32)
    t0 += 16;
  }

#undef LOADR
#undef WAITR
#undef COPYD
#undef LOADB
#undef STA
#undef STB
#undef STAB
#undef RESC
#undef STGAB
#undef WIN16
#undef WIN16G
#undef SWAPB

  A_[2 * lane] = s0A;
  A_[2 * lane + 1] = s1A;
  A_[132 + 2 * lane] = s0B;
  A_[132 + 2 * lane + 1] = s1B;
  if (lane == 63) { A_[128] = s2A; A_[132 + 128] = s2B; }
  __syncthreads();
  if (lane == 0) {
    int slA = 2 * llA;
    float a1 = A_[slA];
    float a2 = (slA >= 1) ? A_[slA - 1] : 0.0f;
    loss[bA] = -(logf(a1 + a2) + (float)acc_eA * LN2);
    if (hasB) {
      int slB = 2 * llB;
      float b1 = A_[132 + slB];
      float b2 = (slB >= 1) ? A_[132 + slB - 1] : 0.0f;
      loss[bB] = -(logf(b1 + b2) + (float)acc_eB * LN2);
    }
  }
}

// ============================================================================
// Kernel 3: sum per-batch losses -> d_out[0]
// ============================================================================
__global__ __launch_bounds__(64) void k_sum(const float* __restrict__ loss,
                                            float* __restrict__ out, int B) {
  int lane = threadIdx.x;
  float s = 0.0f;
  for (int i = lane; i < B; i += 64) s += loss[i];
#pragma unroll
  for (int off = 32; off >= 1; off >>= 1) s += __shfl_xor(s, off, 64);
  if (lane == 0) out[0] = s;
}

extern "C" void kernel_launch(void* const* d_in, const int* in_sizes, int n_in,
                              void* d_out, int out_size, void* d_ws, size_t ws_size,
                              hipStream_t stream) {
  const float* acts       = (const float*)d_in[0];
  const int*   labels     = (const int*)d_in[1];
  const int*   act_lens   = (const int*)d_in[2];
  const int*   label_lens = (const int*)d_in[3];

  const int B = in_sizes[2];
  const int L = in_sizes[1] / B;
  const int T = 1000;   // per reference setup_inputs
  const int V = (int)((long long)in_sizes[0] / ((long long)T * (long long)B));
  const int Tp = (T + 31) & ~31;   // padded channel stride (1024 for T=1000)

  float* lp    = (float*)d_ws;                              // B*(L+1)*Tp floats
  float* lossb = lp + (size_t)B * (size_t)(L + 1) * (size_t)Tp;

  k_prob_gather<<<dim3((T * B + 3) / 4), dim3(256), 0, stream>>>(
      acts, labels, lp, T, Tp, B, V, L);
  k_ctc_fwd<<<dim3((B + 1) / 2), dim3(64), 0, stream>>>(
      lp, labels, act_lens, label_lens, lossb, T, Tp, B, L);
  k_sum<<<dim3(1), dim3(64), 0, stream>>>(lossb, (float*)d_out, B);
}

// Round 19
// 116.354 us; speedup vs baseline: 4.1064x; 1.4119x over previous
//
#include <hip/hip_runtime.h>
#include <stdint.h>

#define LOG2E  1.4426950408889634f
#define LN2    0.6931471805599453f
#define BIAS_E 32   // deferred-rescale normalization target: 2^BIAS_E

// lane i <- lane i-1 (wave_shr:1 = 0x138), lane 0 <- 0.0f (bound_ctrl=true)
__device__ __forceinline__ float dpp_shr1_z(float x) {
  int r = __builtin_amdgcn_update_dpp(0, __float_as_int(x), 0x138, 0xf, 0xf, true);
  return __int_as_float(r);
}

template <int CTRL>
__device__ __forceinline__ float dpp_max(float v) {
  int r = __builtin_amdgcn_update_dpp(0, __float_as_int(v), CTRL, 0xf, 0xf, true);
  return fmaxf(v, __int_as_float(r));
}

// wave64 max reduce -> uniform value (lane63 readlane). alpha >= 0 so 0-fill ok.
__device__ __forceinline__ float wave_max_uniform(float v) {
  v = dpp_max<0x111>(v);   // row_shr:1
  v = dpp_max<0x112>(v);   // row_shr:2
  v = dpp_max<0x114>(v);   // row_shr:4
  v = dpp_max<0x118>(v);   // row_shr:8
  v = dpp_max<0x142>(v);   // row_bcast15
  v = dpp_max<0x143>(v);   // row_bcast31 -> lane 63 = global max
  int gm = __builtin_amdgcn_readlane(__float_as_int(v), 63);
  return __int_as_float(gm);
}

// ============================================================================
// Kernel 1: per (t,b) row: softmax over V, emit LINEAR probs into the
// WINDOW-BLOCK INTERLEAVED layout lp[b][w][c][k], w = t/16, k = t%16,
// c = 0 blank / 1..L labels; block = (L+1)*16 floats. k2's per-window label
// load is then 16 CONTIGUOUS floats per lane (4 cache lines per window for
// the whole wave) instead of a 64-way 4KB-stride gather.
// ============================================================================
__global__ __launch_bounds__(256) void k_prob_gather(
    const float* __restrict__ acts, const int* __restrict__ labels,
    float* __restrict__ lp, int T, int NWB, int B, int V, int L) {
  const int lane = threadIdx.x & 63;
  const uint32_t r = blockIdx.x * 4u + (threadIdx.x >> 6);
  if (r >= (uint32_t)(T * B)) return;
  const uint32_t b = r / (uint32_t)T;
  const uint32_t t = r % (uint32_t)T;
  const float* __restrict__ row = acts + ((size_t)t * (size_t)B + b) * (size_t)V;

  float mx, l2s;
  if (V == 2048) {
    const float4* row4 = (const float4*)row;
    float vals[32];
    mx = -3.0e38f;
#pragma unroll
    for (int q = 0; q < 8; ++q) {
      float4 v = row4[lane + (q << 6)];
      vals[q*4+0] = v.x; vals[q*4+1] = v.y; vals[q*4+2] = v.z; vals[q*4+3] = v.w;
      mx = fmaxf(mx, fmaxf(fmaxf(v.x, v.y), fmaxf(v.z, v.w)));
    }
#pragma unroll
    for (int off = 32; off >= 1; off >>= 1) mx = fmaxf(mx, __shfl_xor(mx, off, 64));
    float s = 0.0f;
#pragma unroll
    for (int k = 0; k < 32; ++k) s += exp2f((vals[k] - mx) * LOG2E);
#pragma unroll
    for (int off = 32; off >= 1; off >>= 1) s += __shfl_xor(s, off, 64);
    l2s = log2f(s);
  } else {
    float m = -3.0e38f, s = 0.0f;
    for (int i = lane; i < V; i += 64) {
      float x = row[i];
      float m2 = fmaxf(m, x);
      s = s * exp2f((m - m2) * LOG2E) + exp2f((x - m2) * LOG2E);
      m = m2;
    }
#pragma unroll
    for (int off = 32; off >= 1; off >>= 1) {
      float mo = __shfl_xor(m, off, 64), so = __shfl_xor(s, off, 64);
      float m2 = fmaxf(m, mo);
      s = s * exp2f((m - m2) * LOG2E) + so * exp2f((mo - m2) * LOG2E);
      m = m2;
    }
    mx = m;
    l2s = log2f(s);
  }

  const int w = (int)(t >> 4), k = (int)(t & 15);
  const size_t WBLK = (size_t)(L + 1) * 16;
  float* __restrict__ out = lp + ((size_t)b * (size_t)NWB + (size_t)w) * WBLK;
  if (lane < L) {
    int lab = labels[b * (uint32_t)L + lane];
    out[(size_t)(1 + lane) * 16 + k] = exp2f((row[lab] - mx) * LOG2E - l2s);
  }
  if (lane == 0) out[k] = exp2f((row[0] - mx) * LOG2E - l2s);
}

// ============================================================================
// Kernel 2: CTC forward, LINEAR domain, deferred+biased power-of-2 rescale
// (round-14 numerics). ZERO INLINE ASM in the loop: rounds 10/17/18's
// intermittent small corruption is attributed to allocator copies of
// asm-output registers while loads were in flight (codegen-luck UB). With
// the window-block layout the label window is 16 contiguous floats, so BOTH
// streams use the plain-C float4 double-buffer pattern that passed 4 rounds
// for the blank stream (ql/nl + qb/nb, issued one window ahead).
// ============================================================================
__global__ __launch_bounds__(64, 1) void k_ctc_fwd(
    const float* __restrict__ lp, const int* __restrict__ labels,
    const int* __restrict__ act_lens, const int* __restrict__ label_lens,
    float* __restrict__ loss, int T, int NWB, int B, int L) {
  const int b = blockIdx.x;
  const int lane = threadIdx.x;
  const int Tact = __builtin_amdgcn_readfirstlane(min(act_lens[b], T));
  const int ll   = __builtin_amdgcn_readfirstlane(min(label_lens[b], L));

  const size_t WBLK = (size_t)(L + 1) * 16;
  const float* __restrict__ chblk = lp + (size_t)b * (size_t)NWB * WBLK;
  const int lclamp = (lane < L) ? lane : (L - 1);
  const int wmax = NWB - 1;

  int lab_i = (lane < L) ? labels[(size_t)b * L + lane] : 0;
  int lab_p = (lane >= 1 && lane - 1 < L) ? labels[(size_t)b * L + lane - 1] : -1;
  const bool allow2 = (lane >= 1) && (lab_i != 0) && (lab_i != lab_p);

  __shared__ float A_[132];

  float4 ql0, ql1, ql2, ql3;   // label window, current
  float4 nl0, nl1, nl2, nl3;   // label window, next (prefetch)
  float4 qb0, qb1, qb2, qb3;   // blank window, current
  float4 nb0, nb1, nb2, nb3;   // blank window, next (prefetch)
  int acc_e = 0;
  int pend_e = 0;
  float pend_sc = 1.0f;

  // label channel of window wc: 16 contiguous floats at wbase + (1+lclamp)*16
#define LOADL(D, wc) { int w_ = (wc); if (w_ > wmax) w_ = wmax;              \
    const float4* p4 = (const float4*)(chblk + (size_t)w_ * WBLK             \
                                       + (size_t)(1 + lclamp) * 16);         \
    D##0 = p4[0]; D##1 = p4[1]; D##2 = p4[2]; D##3 = p4[3]; }

  // blank channel of window wc: 16 contiguous floats at wbase
#define LOADB(D, wc) { int w_ = (wc); if (w_ > wmax) w_ = wmax;              \
    const float4* p4 = (const float4*)(chblk + (size_t)w_ * WBLK);           \
    D##0 = p4[0]; D##1 = p4[1]; D##2 = p4[2]; D##3 = p4[3]; }

  // linear step: ns0=(s0+pa)*pb ; ns1=((s0+s1)+cc)*pl ; ns2=(s2+s1)*pb
#define ST(PB, PL) { float pa = dpp_shr1_z(s1);                              \
    float cc = allow2 ? pa : 0.0f;                                           \
    float n0 = (s0 + pa) * (PB);                                             \
    float n1 = ((s0 + s1) + cc) * (PL);                                      \
    float n2 = (s2 + s1) * (PB);                                             \
    s0 = n0; s1 = n1; s2 = n2; }

  // deferred+biased rescale: apply previous group's exact 2^-pend_e, then
  // start this group's reduce (consumed next group -> off critical path)
#define RESC { s0 *= pend_sc; s1 *= pend_sc; s2 *= pend_sc; acc_e += pend_e; \
    float gm = wave_max_uniform(fmaxf(fmaxf(s0, s1), s2));                   \
    int e = ((__float_as_int(gm) >> 23) & 0xff) - 127 - BIAS_E;              \
    if (e < -126) e = -126;                                                  \
    pend_e = e;                                                              \
    pend_sc = __int_as_float((127 - e) << 23); }

#define STG(PB, PL, tt) { if ((tt) >= 1 && (tt) < Tact) ST(PB, PL) }

#define WIN16 {                                                              \
    ST(qb0.x, ql0.x) ST(qb0.y, ql0.y) ST(qb0.z, ql0.z) ST(qb0.w, ql0.w) RESC \
    ST(qb1.x, ql1.x) ST(qb1.y, ql1.y) ST(qb1.z, ql1.z) ST(qb1.w, ql1.w) RESC \
    ST(qb2.x, ql2.x) ST(qb2.y, ql2.y) ST(qb2.z, ql2.z) ST(qb2.w, ql2.w) RESC \
    ST(qb3.x, ql3.x) ST(qb3.y, ql3.y) ST(qb3.z, ql3.z) ST(qb3.w, ql3.w) RESC }

#define WIN16G(tb) {                                                         \
    STG(qb0.x, ql0.x, (tb)+0)  STG(qb0.y, ql0.y, (tb)+1)                     \
    STG(qb0.z, ql0.z, (tb)+2)  STG(qb0.w, ql0.w, (tb)+3)  RESC               \
    STG(qb1.x, ql1.x, (tb)+4)  STG(qb1.y, ql1.y, (tb)+5)                     \
    STG(qb1.z, ql1.z, (tb)+6)  STG(qb1.w, ql1.w, (tb)+7)  RESC               \
    STG(qb2.x, ql2.x, (tb)+8)  STG(qb2.y, ql2.y, (tb)+9)                     \
    STG(qb2.z, ql2.z, (tb)+10) STG(qb2.w, ql2.w, (tb)+11) RESC               \
    STG(qb3.x, ql3.x, (tb)+12) STG(qb3.y, ql3.y, (tb)+13)                    \
    STG(qb3.z, ql3.z, (tb)+14) STG(qb3.w, ql3.w, (tb)+15) RESC }

#define SWAPQ { ql0 = nl0; ql1 = nl1; ql2 = nl2; ql3 = nl3;                  \
                qb0 = nb0; qb1 = nb1; qb2 = nb2; qb3 = nb3; }

  // ---- prologue: window 0 current, window 1 prefetched ----
  LOADL(ql, 0) LOADB(qb, 0)
  LOADL(nl, 1) LOADB(nb, 1)

  float s0 = (lane == 0) ? qb0.x : 0.0f;   // alpha[0] = p_blank(0)
  float s1 = (lane == 0) ? ql0.x : 0.0f;   // alpha[1] = p_label0(0)
  float s2 = 0.0f;

  WIN16G(0)                   // t=1..15 (t=0 skipped by guard)
  int t0 = 16;

  // ---- main loop: at entry n* = window t0/16 (prefetched last iteration) ----
  while (t0 + 16 <= Tact) {
    const int w = t0 >> 4;
    SWAPQ                     // q* = window w
    LOADL(nl, w + 1)          // prefetch next window (full window of cover)
    LOADB(nb, w + 1)
    WIN16
    t0 += 16;
  }

  // ---- tail: n* = window t0/16 ----
  if (t0 < Tact) {
    SWAPQ
    WIN16G(t0)
  }

#undef LOADL
#undef LOADB
#undef ST
#undef RESC
#undef STG
#undef WIN16
#undef WIN16G
#undef SWAPQ

  A_[2 * lane] = s0;
  A_[2 * lane + 1] = s1;
  if (lane == 63) A_[128] = s2;
  __syncthreads();
  if (lane == 0) {
    int sl = 2 * ll;
    float a1 = A_[sl];
    float a2 = (sl >= 1) ? A_[sl - 1] : 0.0f;
    // true alpha = stored * 2^{acc_e} (pend_* intentionally unapplied)
    loss[b] = -(logf(a1 + a2) + (float)acc_e * LN2);
  }
}

// ============================================================================
// Kernel 3: sum per-batch losses -> d_out[0]
// ============================================================================
__global__ __launch_bounds__(64) void k_sum(const float* __restrict__ loss,
                                            float* __restrict__ out, int B) {
  int lane = threadIdx.x;
  float s = 0.0f;
  for (int i = lane; i < B; i += 64) s += loss[i];
#pragma unroll
  for (int off = 32; off >= 1; off >>= 1) s += __shfl_xor(s, off, 64);
  if (lane == 0) out[0] = s;
}

extern "C" void kernel_launch(void* const* d_in, const int* in_sizes, int n_in,
                              void* d_out, int out_size, void* d_ws, size_t ws_size,
                              hipStream_t stream) {
  const float* acts       = (const float*)d_in[0];
  const int*   labels     = (const int*)d_in[1];
  const int*   act_lens   = (const int*)d_in[2];
  const int*   label_lens = (const int*)d_in[3];

  const int B = in_sizes[2];
  const int L = in_sizes[1] / B;
  const int T = 1000;   // per reference setup_inputs
  const int V = (int)((long long)in_sizes[0] / ((long long)T * (long long)B));
  const int NWB = ((T + 15) / 16 + 3) & ~3;   // window-blocks per batch (64)

  float* lp    = (float*)d_ws;   // B * NWB * (L+1)*16 floats (8.5 MB)
  float* lossb = lp + (size_t)B * (size_t)NWB * (size_t)(L + 1) * 16;

  k_prob_gather<<<dim3((T * B + 3) / 4), dim3(256), 0, stream>>>(
      acts, labels, lp, T, NWB, B, V, L);
  k_ctc_fwd<<<dim3(B), dim3(64), 0, stream>>>(lp, labels, act_lens, label_lens,
                                              lossb, T, NWB, B, L);
  k_sum<<<dim3(1), dim3(64), 0, stream>>>(lossb, (float*)d_out, B);
}